// Round 11
// baseline (532.478 us; speedup 1.0000x reference)
//
#include <hip/hip_runtime.h>
#include <hip/hip_cooperative_groups.h>

namespace cg = cooperative_groups;

// Problem constants: B=1, N=16, T=2048, E=64, H=4, D=16
#define N_ 16
#define T_ 2048
#define E_ 64
#define H_ 4
#define D_ 16
#define NH_ 64            // N_*H_
#define SEXP_ 0.18033688f // 0.125 * log2(e):  exp(s/8) == exp2(s*SEXP_)

typedef __attribute__((ext_vector_type(4))) _Float16 h4;
typedef __attribute__((ext_vector_type(8))) _Float16 h8;
typedef __attribute__((ext_vector_type(2))) __fp16 g2;
typedef __attribute__((ext_vector_type(4))) float f4;

#if __has_builtin(__builtin_amdgcn_exp2f)
__device__ inline float fast_exp2(float x) { return __builtin_amdgcn_exp2f(x); }
#else
__device__ inline float fast_exp2(float x) {
    float r; asm("v_exp_f32 %0, %1" : "=v"(r) : "v"(x)); return r;
}
#endif

__device__ inline h4 pack4_f16(float a, float b, float c, float d) {
    union { g2 g[2]; h4 h; } u;
    u.g[0] = __builtin_amdgcn_cvt_pkrtz(a, b);
    u.g[1] = __builtin_amdgcn_cvt_pkrtz(c, d);
    return u.h;
}

// ===========================================================================
// Cooperative mega-kernel: 1024 blocks x 256, 4 blocks/CU co-resident.
// proj -> sync -> stats(x2 split) -> sync -> attn(rl prologue, x2 split)
//      -> sync -> fc.   Lp: 2 partials. PO: 2 partials.
// ===========================================================================
__global__ __launch_bounds__(256, 4) void mega_kernel(
    const float* __restrict__ xq, const float* __restrict__ Wq, const float* __restrict__ bq,
    const float* __restrict__ xk, const float* __restrict__ Wk, const float* __restrict__ bk,
    const float* __restrict__ xv, const float* __restrict__ Wv, const float* __restrict__ bv,
    const float* __restrict__ Wfc, const float* __restrict__ bfc,
    _Float16* __restrict__ Qh, _Float16* __restrict__ Kh, _Float16* __restrict__ Vt,
    _Float16* __restrict__ Wt, float* __restrict__ Lp, float* __restrict__ PO,
    float* __restrict__ out)
{
    cg::grid_group grid = cg::this_grid();
    int tid = threadIdx.x;
    int lane = tid & 63, wave = tid >> 6;
    int row = lane & 15, quad = lane >> 4;
    int u = blockIdx.x;

    __shared__ float Wl[D_ * D_];
    __shared__ float bl[D_];
    __shared__ __align__(16) _Float16 rlh[1024];

    // ================= Phase P: projections (2 x-units per block) ==========
    {
        int y = u >> 8;                    // 0:Q 1:K 2:V 3:WfcT
        int x0 = (u & 255) * 2;
        if (y == 3) {
#pragma unroll
            for (int xi = 0; xi < 2; xi++) {
                int x = x0 + xi;
                if (x < 16) {
                    int k = x * 4 + (tid >> 6);
                    int e = tid & 63;
                    Wt[e * 64 + k] = (_Float16)Wfc[k * 64 + e];
                }
            }
        } else {
            const float* xx = (y == 0) ? xq : (y == 1) ? xk : xv;
            const float* W  = (y == 0) ? Wq : (y == 1) ? Wk : Wv;
            const float* b  = (y == 0) ? bq : (y == 1) ? bk : bv;
            const float sc  = (y == 0) ? SEXP_ : 1.0f;

            Wl[tid] = W[tid];
            if (tid < D_) bl[tid] = b[tid];
            __syncthreads();

#pragma unroll
            for (int xi = 0; xi < 2; xi++) {
                int r = (x0 + xi) * 256 + tid;
                int h, t, n;
                if (y == 2) {      // t fastest: coalesced transposed stores
                    t = r & (T_ - 1);
                    h = (r >> 11) & (H_ - 1);
                    n = r >> 13;
                } else {           // h fastest: coalesced reads
                    h = r & (H_ - 1);
                    t = (r >> 2) & (T_ - 1);
                    n = r >> 13;
                }
                const float4* xp4 = reinterpret_cast<const float4*>(
                    xx + ((size_t)(n * T_ + t) * E_ + h * D_));
                float xv_[D_];
#pragma unroll
                for (int i = 0; i < 4; i++) {
                    float4 v = xp4[i];
                    xv_[4*i] = v.x; xv_[4*i+1] = v.y; xv_[4*i+2] = v.z; xv_[4*i+3] = v.w;
                }
                float acc[D_];
#pragma unroll
                for (int i = 0; i < D_; i++) acc[i] = bl[i];
#pragma unroll
                for (int j = 0; j < D_; j++) {
                    float xj = xv_[j];
#pragma unroll
                    for (int i = 0; i < D_; i++) acc[i] = fmaf(xj, Wl[j * D_ + i], acc[i]);
                }
                if (y == 2) {
                    _Float16* vb = Vt + (size_t)(n * H_ + h) * D_ * T_ + t;
#pragma unroll
                    for (int d = 0; d < D_; d++) vb[(size_t)d * T_] = (_Float16)acc[d];
                } else {
                    _Float16 ob[16];
#pragma unroll
                    for (int i = 0; i < D_; i++) ob[i] = (_Float16)(acc[i] * sc);
                    _Float16* o = (y == 0) ? Qh : Kh;
                    uint4* dst = reinterpret_cast<uint4*>(o + (size_t)((n * H_ + h) * T_ + t) * D_);
                    dst[0] = reinterpret_cast<uint4*>(ob)[0];
                    dst[1] = reinterpret_cast<uint4*>(ob)[1];
                }
            }
        }
    }
    grid.sync();

    // ================= Phase S: stats, q-split x2 ==========================
    {
        int nh = u >> 4, y = (u >> 1) & 7, z = u & 1;
        int kt0 = (y * 4 + wave) * 4;      // first of 4 k-tiles
        const _Float16* Kb = Kh + (size_t)nh * T_ * D_;
        const _Float16* Qb = Qh + (size_t)nh * T_ * D_;

        h4 a[4];
#pragma unroll
        for (int j = 0; j < 4; j++)
            a[j] = *reinterpret_cast<const h4*>(Kb + ((kt0 + j) * 16 + row) * D_ + quad * 4);

        f4 l[4];
#pragma unroll
        for (int j = 0; j < 4; j++) l[j] = (f4){0.f, 0.f, 0.f, 0.f};
        f4 z4 = {0.f, 0.f, 0.f, 0.f};

        int q_lo = z * (T_ / 2), q_hi = q_lo + T_ / 2;
#pragma unroll 4
        for (int q0 = q_lo; q0 < q_hi; q0 += 16) {
            h4 b = *reinterpret_cast<const h4*>(Qb + (q0 + row) * D_ + quad * 4);
#pragma unroll
            for (int j = 0; j < 4; j++) {
                f4 s = __builtin_amdgcn_mfma_f32_16x16x16f16(a[j], b, z4, 0, 0, 0);
#pragma unroll
                for (int i = 0; i < 4; i++) l[j][i] += fast_exp2(s[i]);
            }
        }
#pragma unroll
        for (int off = 1; off < 16; off <<= 1)
#pragma unroll
            for (int j = 0; j < 4; j++)
#pragma unroll
                for (int i = 0; i < 4; i++)
                    l[j][i] += __shfl_xor(l[j][i], off, 64);

        if (row == 0) {
            float* lp = Lp + ((size_t)z * NH_ + nh) * T_;
#pragma unroll
            for (int j = 0; j < 4; j++)
                *reinterpret_cast<f4*>(lp + (kt0 + j) * 16 + quad * 4) = l[j];
        }
    }
    grid.sync();

    // ================= Phase A: attn, k-split x2 ===========================
    {
        int nh = u >> 4, y = (u >> 1) & 7, z = u & 1;
        int qt0 = (y * 4 + wave) * 4;      // first of 4 q-tiles
        int k_lo = z * (T_ / 2);

        // prologue: rlh[i] = fp16( 1 / (Lp[0][nh][k_lo+i] + Lp[1][nh][k_lo+i]) )
        {
            int kk = tid * 4;
            f4 s0 = *reinterpret_cast<const f4*>(Lp + (size_t)nh * T_ + k_lo + kk);
            f4 s1 = *reinterpret_cast<const f4*>(Lp + ((size_t)NH_ + nh) * T_ + k_lo + kk);
            h4 pk = pack4_f16(1.0f / (s0[0] + s1[0]), 1.0f / (s0[1] + s1[1]),
                              1.0f / (s0[2] + s1[2]), 1.0f / (s0[3] + s1[3]));
            *reinterpret_cast<h4*>(&rlh[kk]) = pk;
        }
        __syncthreads();

        const _Float16* Kb = Kh + (size_t)nh * T_ * D_;
        const _Float16* Qb = Qh + (size_t)nh * T_ * D_;
        const _Float16* Vb = Vt + (size_t)nh * D_ * T_ + (size_t)row * T_;

        h4 b[4];
#pragma unroll
        for (int j = 0; j < 4; j++)
            b[j] = *reinterpret_cast<const h4*>(Qb + ((qt0 + j) * 16 + row) * D_ + quad * 4);

        f4 o[4];
#pragma unroll
        for (int j = 0; j < 4; j++) o[j] = (f4){0.f, 0.f, 0.f, 0.f};
        f4 z4 = {0.f, 0.f, 0.f, 0.f};

        int pr = ((row & 12) << 1) | (row & 3);   // permuted K-row offset

        int k_hi = k_lo + T_ / 2;
#pragma unroll 2
        for (int k0 = k_lo; k0 < k_hi; k0 += 32) {
            h4 a0 = *reinterpret_cast<const h4*>(Kb + (k0 + pr) * D_ + quad * 4);
            h4 a1 = *reinterpret_cast<const h4*>(Kb + (k0 + pr + 4) * D_ + quad * 4);
            h8 v = *reinterpret_cast<const h8*>(Vb + k0 + quad * 8);
            h8 rv = *reinterpret_cast<const h8*>(&rlh[(k0 - k_lo) + quad * 8]);
            v = v * rv;                            // fold 1/l into V fragment
#pragma unroll
            for (int j = 0; j < 4; j++) {
                f4 s0 = __builtin_amdgcn_mfma_f32_16x16x16f16(a0, b[j], z4, 0, 0, 0);
                f4 s1 = __builtin_amdgcn_mfma_f32_16x16x16f16(a1, b[j], z4, 0, 0, 0);
                union { h4 h[2]; h8 h8v; } p;
                p.h[0] = pack4_f16(fast_exp2(s0[0]), fast_exp2(s0[1]),
                                   fast_exp2(s0[2]), fast_exp2(s0[3]));
                p.h[1] = pack4_f16(fast_exp2(s1[0]), fast_exp2(s1[1]),
                                   fast_exp2(s1[2]), fast_exp2(s1[3]));
                o[j] = __builtin_amdgcn_mfma_f32_16x16x32_f16(p.h8v, v, o[j], 0, 0, 0);
            }
        }
        int n = nh >> 2, h = nh & 3;
        float* po = PO + (size_t)z * N_ * T_ * E_ + (size_t)n * T_ * E_ + h * D_ + row;
#pragma unroll
        for (int j = 0; j < 4; j++)
#pragma unroll
            for (int i = 0; i < 4; i++) {
                int q0 = (qt0 + j) * 16 + quad * 4 + i;
                po[(size_t)q0 * E_] = o[j][i];
            }
    }
    grid.sync();

    // ================= Phase F: fc (2 M-tiles per block) ===================
    {
        const size_t zstride = (size_t)N_ * T_ * E_ / 4;   // f4 units
        int ne = wave;
#pragma unroll
        for (int ti = 0; ti < 2; ti++) {
            int r0 = (u * 2 + ti) * 16;
            size_t base = (size_t)(r0 + row) * E_;

            h8 a[2];
#pragma unroll
            for (int half = 0; half < 2; half++) {
                const f4* p0 = reinterpret_cast<const f4*>(PO) + base / 4;
                const f4* p1 = p0 + zstride;
                f4 w0 = p0[half * 8 + quad * 2], w1 = p0[half * 8 + quad * 2 + 1];
                f4 v0 = p1[half * 8 + quad * 2], v1 = p1[half * 8 + quad * 2 + 1];
                union { h4 h[2]; h8 v; } pk;
                pk.h[0] = pack4_f16(w0[0] + v0[0], w0[1] + v0[1], w0[2] + v0[2], w0[3] + v0[3]);
                pk.h[1] = pack4_f16(w1[0] + v1[0], w1[1] + v1[1], w1[2] + v1[2], w1[3] + v1[3]);
                a[half] = pk.v;
            }
            const _Float16* wtb = Wt + (size_t)(ne * 16 + row) * 64;
            h8 b0 = *reinterpret_cast<const h8*>(wtb + quad * 8);
            h8 b1 = *reinterpret_cast<const h8*>(wtb + 32 + quad * 8);
            f4 acc = __builtin_amdgcn_mfma_f32_16x16x32_f16(a[0], b0, (f4){0.f,0.f,0.f,0.f}, 0, 0, 0);
            acc = __builtin_amdgcn_mfma_f32_16x16x32_f16(a[1], b1, acc, 0, 0, 0);

            float bias = bfc[ne * 16 + row];
#pragma unroll
            for (int i = 0; i < 4; i++)
                out[(size_t)(r0 + quad * 4 + i) * E_ + ne * 16 + row] = acc[i] + bias;
        }
    }
}

// ===========================================================================
// Fallback path (R9, proven 176 us): separate kernels, 4-way splits.
// ===========================================================================
__global__ __launch_bounds__(256) void proj_kernel(
    const float* __restrict__ xq, const float* __restrict__ Wq, const float* __restrict__ bq,
    const float* __restrict__ xk, const float* __restrict__ Wk, const float* __restrict__ bk,
    const float* __restrict__ xv, const float* __restrict__ Wv, const float* __restrict__ bv,
    const float* __restrict__ Wfc,
    _Float16* __restrict__ Qh, _Float16* __restrict__ Kh, _Float16* __restrict__ Vt,
    _Float16* __restrict__ Wt)
{
    int tid = threadIdx.x;
    int y = blockIdx.y;
    if (y == 3) {
        if (blockIdx.x < 16) {
            int k = blockIdx.x * 4 + (tid >> 6);
            int e = tid & 63;
            Wt[e * 64 + k] = (_Float16)Wfc[k * 64 + e];
        }
        return;
    }
    const float* x = (y == 0) ? xq : (y == 1) ? xk : xv;
    const float* W = (y == 0) ? Wq : (y == 1) ? Wk : Wv;
    const float* b = (y == 0) ? bq : (y == 1) ? bk : bv;
    const float sc = (y == 0) ? SEXP_ : 1.0f;

    __shared__ float Wl[D_ * D_];
    __shared__ float bl[D_];
    Wl[tid] = W[tid];
    if (tid < D_) bl[tid] = b[tid];
    __syncthreads();

    int r = blockIdx.x * 256 + tid;
    int h, t, n;
    if (y == 2) {
        t = r & (T_ - 1);
        h = (r >> 11) & (H_ - 1);
        n = r >> 13;
    } else {
        h = r & (H_ - 1);
        t = (r >> 2) & (T_ - 1);
        n = r >> 13;
    }
    const float4* xp4 = reinterpret_cast<const float4*>(
        x + ((size_t)(n * T_ + t) * E_ + h * D_));
    float xv_[D_];
#pragma unroll
    for (int i = 0; i < 4; i++) {
        float4 v = xp4[i];
        xv_[4*i] = v.x; xv_[4*i+1] = v.y; xv_[4*i+2] = v.z; xv_[4*i+3] = v.w;
    }
    float acc[D_];
#pragma unroll
    for (int i = 0; i < D_; i++) acc[i] = bl[i];
#pragma unroll
    for (int j = 0; j < D_; j++) {
        float xj = xv_[j];
#pragma unroll
        for (int i = 0; i < D_; i++) acc[i] = fmaf(xj, Wl[j * D_ + i], acc[i]);
    }
    if (y == 2) {
        _Float16* vb = Vt + (size_t)(n * H_ + h) * D_ * T_ + t;
#pragma unroll
        for (int d = 0; d < D_; d++) vb[(size_t)d * T_] = (_Float16)acc[d];
    } else {
        _Float16 ob[16];
#pragma unroll
        for (int i = 0; i < D_; i++) ob[i] = (_Float16)(acc[i] * sc);
        _Float16* o = (y == 0) ? Qh : Kh;
        uint4* dst = reinterpret_cast<uint4*>(o + (size_t)((n * H_ + h) * T_ + t) * D_);
        dst[0] = reinterpret_cast<uint4*>(ob)[0];
        dst[1] = reinterpret_cast<uint4*>(ob)[1];
    }
}

__global__ __launch_bounds__(256) void stats_kernel(
    const _Float16* __restrict__ Qh, const _Float16* __restrict__ Kh,
    float* __restrict__ Lp)
{
    int tid = threadIdx.x;
    int lane = tid & 63, wave = tid >> 6;
    int row = lane & 15, quad = lane >> 4;
    int nh = blockIdx.x;
    int kt0 = (blockIdx.y * 4 + wave) * 4;
    int z = blockIdx.z;
    const _Float16* Kb = Kh + (size_t)nh * T_ * D_;
    const _Float16* Qb = Qh + (size_t)nh * T_ * D_;

    h4 a[4];
#pragma unroll
    for (int j = 0; j < 4; j++)
        a[j] = *reinterpret_cast<const h4*>(Kb + ((kt0 + j) * 16 + row) * D_ + quad * 4);
    f4 l[4];
#pragma unroll
    for (int j = 0; j < 4; j++) l[j] = (f4){0.f, 0.f, 0.f, 0.f};
    f4 z4 = {0.f, 0.f, 0.f, 0.f};

    int q_lo = z * (T_ / 4), q_hi = q_lo + T_ / 4;
#pragma unroll 4
    for (int q0 = q_lo; q0 < q_hi; q0 += 16) {
        h4 b = *reinterpret_cast<const h4*>(Qb + (q0 + row) * D_ + quad * 4);
#pragma unroll
        for (int j = 0; j < 4; j++) {
            f4 s = __builtin_amdgcn_mfma_f32_16x16x16f16(a[j], b, z4, 0, 0, 0);
#pragma unroll
            for (int i = 0; i < 4; i++) l[j][i] += fast_exp2(s[i]);
        }
    }
#pragma unroll
    for (int off = 1; off < 16; off <<= 1)
#pragma unroll
        for (int j = 0; j < 4; j++)
#pragma unroll
            for (int i = 0; i < 4; i++)
                l[j][i] += __shfl_xor(l[j][i], off, 64);
    if (row == 0) {
        float* lp = Lp + ((size_t)z * NH_ + nh) * T_;
#pragma unroll
        for (int j = 0; j < 4; j++)
            *reinterpret_cast<f4*>(lp + (kt0 + j) * 16 + quad * 4) = l[j];
    }
}

__global__ __launch_bounds__(256) void combine_kernel(
    const float* __restrict__ Lp, _Float16* __restrict__ Vt)
{
    int nh = blockIdx.x >> 1;
    int k0 = (blockIdx.x & 1) * 1024 + threadIdx.x * 4;
    f4 s = {0.f, 0.f, 0.f, 0.f};
#pragma unroll
    for (int zz = 0; zz < 4; zz++) {
        f4 lv = *reinterpret_cast<const f4*>(Lp + ((size_t)zz * NH_ + nh) * T_ + k0);
        s[0] += lv[0]; s[1] += lv[1]; s[2] += lv[2]; s[3] += lv[3];
    }
    f4 r;
#pragma unroll
    for (int i = 0; i < 4; i++) r[i] = 1.0f / s[i];
    _Float16* vb = Vt + (size_t)nh * D_ * T_ + k0;
#pragma unroll
    for (int d = 0; d < D_; d++) {
        union { uint2 u; _Float16 hh[4]; } v;
        v.u = *reinterpret_cast<const uint2*>(vb + (size_t)d * T_);
        h4 sv = pack4_f16((float)v.hh[0] * r[0], (float)v.hh[1] * r[1],
                          (float)v.hh[2] * r[2], (float)v.hh[3] * r[3]);
        union { h4 h; uint2 u; } o; o.h = sv;
        *reinterpret_cast<uint2*>(vb + (size_t)d * T_) = o.u;
    }
}

__global__ __launch_bounds__(256) void attn_kernel(
    const _Float16* __restrict__ Qh, const _Float16* __restrict__ Kh,
    const _Float16* __restrict__ Vsc, float* __restrict__ PO)
{
    int tid = threadIdx.x;
    int lane = tid & 63, wave = tid >> 6;
    int row = lane & 15, quad = lane >> 4;
    int nh = blockIdx.x;
    int qt0 = (blockIdx.y * 4 + wave) * 4;
    int z = blockIdx.z;
    const _Float16* Kb = Kh + (size_t)nh * T_ * D_;
    const _Float16* Qb = Qh + (size_t)nh * T_ * D_;
    const _Float16* Vb = Vsc + (size_t)nh * D_ * T_ + (size_t)row * T_;

    h4 b[4];
#pragma unroll
    for (int j = 0; j < 4; j++)
        b[j] = *reinterpret_cast<const h4*>(Qb + ((qt0 + j) * 16 + row) * D_ + quad * 4);
    f4 o[4];
#pragma unroll
    for (int j = 0; j < 4; j++) o[j] = (f4){0.f, 0.f, 0.f, 0.f};
    f4 z4 = {0.f, 0.f, 0.f, 0.f};
    int pr = ((row & 12) << 1) | (row & 3);

    int k_lo = z * (T_ / 4), k_hi = k_lo + T_ / 4;
#pragma unroll 2
    for (int k0 = k_lo; k0 < k_hi; k0 += 32) {
        h4 a0 = *reinterpret_cast<const h4*>(Kb + (k0 + pr) * D_ + quad * 4);
        h4 a1 = *reinterpret_cast<const h4*>(Kb + (k0 + pr + 4) * D_ + quad * 4);
        h8 v = *reinterpret_cast<const h8*>(Vb + k0 + quad * 8);
#pragma unroll
        for (int j = 0; j < 4; j++) {
            f4 s0 = __builtin_amdgcn_mfma_f32_16x16x16f16(a0, b[j], z4, 0, 0, 0);
            f4 s1 = __builtin_amdgcn_mfma_f32_16x16x16f16(a1, b[j], z4, 0, 0, 0);
            union { h4 h[2]; h8 h8v; } p;
            p.h[0] = pack4_f16(fast_exp2(s0[0]), fast_exp2(s0[1]),
                               fast_exp2(s0[2]), fast_exp2(s0[3]));
            p.h[1] = pack4_f16(fast_exp2(s1[0]), fast_exp2(s1[1]),
                               fast_exp2(s1[2]), fast_exp2(s1[3]));
            o[j] = __builtin_amdgcn_mfma_f32_16x16x32_f16(p.h8v, v, o[j], 0, 0, 0);
        }
    }
    int n = nh >> 2, h = nh & 3;
    float* po = PO + (size_t)z * N_ * T_ * E_ + (size_t)n * T_ * E_ + h * D_ + row;
#pragma unroll
    for (int j = 0; j < 4; j++)
#pragma unroll
        for (int i = 0; i < 4; i++) {
            int q0 = (qt0 + j) * 16 + quad * 4 + i;
            po[(size_t)q0 * E_] = o[j][i];
        }
}

__global__ __launch_bounds__(256) void fc_kernel(
    const float* __restrict__ PO, const _Float16* __restrict__ Wt,
    const float* __restrict__ bfc, float* __restrict__ out)
{
    int tid = threadIdx.x;
    int lane = tid & 63, wave = tid >> 6;
    int row = lane & 15, quad = lane >> 4;
    int g = blockIdx.x * 4 + wave;
    int r0 = g * 16;
    size_t base = (size_t)(r0 + row) * E_;
    const size_t zstride = (size_t)N_ * T_ * E_ / 4;

    h8 a[2];
#pragma unroll
    for (int half = 0; half < 2; half++) {
        f4 u0 = {0.f,0.f,0.f,0.f}, u1 = {0.f,0.f,0.f,0.f};
#pragma unroll
        for (int zz = 0; zz < 4; zz++) {
            const f4* p = reinterpret_cast<const f4*>(PO) + zz * zstride + base / 4;
            f4 w0 = p[half * 8 + quad * 2];
            f4 w1 = p[half * 8 + quad * 2 + 1];
#pragma unroll
            for (int i = 0; i < 4; i++) { u0[i] += w0[i]; u1[i] += w1[i]; }
        }
        union { h4 h[2]; h8 v; } pk;
        pk.h[0] = pack4_f16(u0[0], u0[1], u0[2], u0[3]);
        pk.h[1] = pack4_f16(u1[0], u1[1], u1[2], u1[3]);
        a[half] = pk.v;
    }
    f4 acc[4];
#pragma unroll
    for (int ne = 0; ne < 4; ne++) {
        const _Float16* wtb = Wt + (size_t)(ne * 16 + row) * 64;
        h8 b0 = *reinterpret_cast<const h8*>(wtb + quad * 8);
        h8 b1 = *reinterpret_cast<const h8*>(wtb + 32 + quad * 8);
        acc[ne] = __builtin_amdgcn_mfma_f32_16x16x32_f16(a[0], b0, (f4){0.f,0.f,0.f,0.f}, 0, 0, 0);
        acc[ne] = __builtin_amdgcn_mfma_f32_16x16x32_f16(a[1], b1, acc[ne], 0, 0, 0);
    }
#pragma unroll
    for (int ne = 0; ne < 4; ne++) {
        float bias = bfc[ne * 16 + row];
#pragma unroll
        for (int i = 0; i < 4; i++)
            out[(size_t)(r0 + quad * 4 + i) * E_ + ne * 16 + row] = acc[ne][i] + bias;
    }
}

extern "C" void kernel_launch(void* const* d_in, const int* in_sizes, int n_in,
                              void* d_out, int out_size, void* d_ws, size_t ws_size,
                              hipStream_t stream) {
    (void)in_sizes; (void)n_in; (void)out_size; (void)ws_size;
    const float* value = (const float*)d_in[0];
    const float* key   = (const float*)d_in[1];
    const float* query = (const float*)d_in[2];
    const float* Wq    = (const float*)d_in[3];
    const float* bq    = (const float*)d_in[4];
    const float* Wk    = (const float*)d_in[5];
    const float* bk    = (const float*)d_in[6];
    const float* Wv    = (const float*)d_in[7];
    const float* bv    = (const float*)d_in[8];
    const float* Wfc   = (const float*)d_in[9];
    const float* bfc   = (const float*)d_in[10];
    float* out = (float*)d_out;

    // ws bytes: Qh 0-4M | Kh 4-8M | Vt 8-12M | Wt 12M | Lp 13-15M | PO 15-47M
    char* ws = (char*)d_ws;
    _Float16* Qh  = (_Float16*)(ws);
    _Float16* Kh  = (_Float16*)(ws + (4u << 20));
    _Float16* Vt  = (_Float16*)(ws + (8u << 20));
    _Float16* Wt  = (_Float16*)(ws + (12u << 20));
    float*    Lp  = (float*)   (ws + (13u << 20));
    float*    PO  = (float*)   (ws + (15u << 20));

    void* args[] = { &query, &Wq, &bq, &key, &Wk, &bk, &value, &Wv, &bv,
                     &Wfc, &bfc, &Qh, &Kh, &Vt, &Wt, &Lp, &PO, &out };
    hipError_t err = hipLaunchCooperativeKernel(
        reinterpret_cast<void*>(mega_kernel), dim3(1024), dim3(256), args, 0, stream);
    if (err != hipSuccess) {
        // deterministic fallback: proven R9 5-kernel path
        (void)hipGetLastError();   // clear sticky error
        proj_kernel<<<dim3(512, 4), 256, 0, stream>>>(
            query, Wq, bq, key, Wk, bk, value, Wv, bv, Wfc, Qh, Kh, Vt, Wt);
        stats_kernel<<<dim3(NH_, 8, 4), 256, 0, stream>>>(Qh, Kh, Lp);
        combine_kernel<<<128, 256, 0, stream>>>(Lp, Vt);
        attn_kernel<<<dim3(NH_, 8, 4), 256, 0, stream>>>(Qh, Kh, Vt, PO);
        fc_kernel<<<512, 256, 0, stream>>>(PO, Wt, bfc, out);
    }
}

// Round 12
// 229.170 us; speedup vs baseline: 2.3235x; 2.3235x over previous
//
#include <hip/hip_runtime.h>

// Problem constants: B=1, N=16, T=2048, E=64, H=4, D=16
#define N_ 16
#define T_ 2048
#define E_ 64
#define H_ 4
#define D_ 16
#define NH_ 64            // N_*H_
#define SEXP_ 0.18033688f // 0.125 * log2(e):  exp(s/8) == exp2(s*SEXP_)

typedef __attribute__((ext_vector_type(4))) _Float16 h4;
typedef __attribute__((ext_vector_type(8))) _Float16 h8;
typedef __attribute__((ext_vector_type(2))) __fp16 g2;
typedef __attribute__((ext_vector_type(4))) float f4;

#if __has_builtin(__builtin_amdgcn_exp2f)
__device__ inline float fast_exp2(float x) { return __builtin_amdgcn_exp2f(x); }
#else
__device__ inline float fast_exp2(float x) {
    float r; asm("v_exp_f32 %0, %1" : "=v"(r) : "v"(x)); return r;
}
#endif

__device__ inline h4 pack4_f16(float a, float b, float c, float d) {
    union { g2 g[2]; h4 h; } u;
    u.g[0] = __builtin_amdgcn_cvt_pkrtz(a, b);
    u.g[1] = __builtin_amdgcn_cvt_pkrtz(c, d);
    return u.h;
}

// ---------------------------------------------------------------------------
// K1: fused projections (y=0 Q pre-scaled, y=1 K, y=2 V-transposed, y=3 Wfc^T)
// ---------------------------------------------------------------------------
__global__ __launch_bounds__(256) void proj_kernel(
    const float* __restrict__ xq, const float* __restrict__ Wq, const float* __restrict__ bq,
    const float* __restrict__ xk, const float* __restrict__ Wk, const float* __restrict__ bk,
    const float* __restrict__ xv, const float* __restrict__ Wv, const float* __restrict__ bv,
    const float* __restrict__ Wfc,
    _Float16* __restrict__ Qh, _Float16* __restrict__ Kh, _Float16* __restrict__ Vt,
    _Float16* __restrict__ Wt)
{
    int tid = threadIdx.x;
    int y = blockIdx.y;
    if (y == 3) {
        if (blockIdx.x < 16) {
            int k = blockIdx.x * 4 + (tid >> 6);
            int e = tid & 63;
            Wt[e * 64 + k] = (_Float16)Wfc[k * 64 + e];
        }
        return;
    }
    const float* x = (y == 0) ? xq : (y == 1) ? xk : xv;
    const float* W = (y == 0) ? Wq : (y == 1) ? Wk : Wv;
    const float* b = (y == 0) ? bq : (y == 1) ? bk : bv;
    const float sc = (y == 0) ? SEXP_ : 1.0f;

    __shared__ float Wl[D_ * D_];
    __shared__ float bl[D_];
    Wl[tid] = W[tid];
    if (tid < D_) bl[tid] = b[tid];
    __syncthreads();

    int r = blockIdx.x * 256 + tid;
    int h, t, n;
    if (y == 2) {          // t fastest: coalesced transposed stores
        t = r & (T_ - 1);
        h = (r >> 11) & (H_ - 1);
        n = r >> 13;
    } else {               // h fastest: coalesced reads
        h = r & (H_ - 1);
        t = (r >> 2) & (T_ - 1);
        n = r >> 13;
    }

    const float4* xp4 = reinterpret_cast<const float4*>(
        x + ((size_t)(n * T_ + t) * E_ + h * D_));
    float xv_[D_];
#pragma unroll
    for (int i = 0; i < 4; i++) {
        float4 v = xp4[i];
        xv_[4*i] = v.x; xv_[4*i+1] = v.y; xv_[4*i+2] = v.z; xv_[4*i+3] = v.w;
    }
    float acc[D_];
#pragma unroll
    for (int i = 0; i < D_; i++) acc[i] = bl[i];
#pragma unroll
    for (int j = 0; j < D_; j++) {
        float xj = xv_[j];
#pragma unroll
        for (int i = 0; i < D_; i++) acc[i] = fmaf(xj, Wl[j * D_ + i], acc[i]);
    }
    if (y == 2) {
        _Float16* vb = Vt + (size_t)(n * H_ + h) * D_ * T_ + t;
#pragma unroll
        for (int d = 0; d < D_; d++) vb[(size_t)d * T_] = (_Float16)acc[d];
    } else {
        _Float16 ob[16];
#pragma unroll
        for (int i = 0; i < D_; i++) ob[i] = (_Float16)(acc[i] * sc);
        _Float16* o = (y == 0) ? Qh : Kh;
        uint4* dst = reinterpret_cast<uint4*>(o + (size_t)((n * H_ + h) * T_ + t) * D_);
        dst[0] = reinterpret_cast<uint4*>(ob)[0];
        dst[1] = reinterpret_cast<uint4*>(ob)[1];
    }
}

// ---------------------------------------------------------------------------
// K2: stats — partial column sums Lp[z][nh][k] = sum_{q in z-chunk} exp2(S')
//     4 k-tiles/wave, q-split x4, manual unroll x4 (imm-offset loads).
//     grid (NH, 8, 4) x 256.
// ---------------------------------------------------------------------------
__global__ __launch_bounds__(256, 8) void stats_kernel(
    const _Float16* __restrict__ Qh, const _Float16* __restrict__ Kh,
    float* __restrict__ Lp)
{
    int tid = threadIdx.x;
    int lane = tid & 63, wave = tid >> 6;
    int row = lane & 15, quad = lane >> 4;
    int nh = blockIdx.x;
    int kt0 = (blockIdx.y * 4 + wave) * 4;    // first of 4 k-tiles
    int z = blockIdx.z;
    const _Float16* Kb = Kh + (size_t)nh * T_ * D_;
    const _Float16* Qb = Qh + (size_t)nh * T_ * D_;

    h4 a[4];
#pragma unroll
    for (int j = 0; j < 4; j++)
        a[j] = *reinterpret_cast<const h4*>(Kb + ((kt0 + j) * 16 + row) * D_ + quad * 4);

    f4 l[4];
#pragma unroll
    for (int j = 0; j < 4; j++) l[j] = (f4){0.f, 0.f, 0.f, 0.f};
    f4 z4 = {0.f, 0.f, 0.f, 0.f};

    int q_lo = z * (T_ / 4);
    const _Float16* qp = Qb + (size_t)(q_lo + row) * D_ + quad * 4;
    for (int it = 0; it < (T_ / 4) / 64; it++) {       // 8 outer iters, 4x16q each
#pragma unroll
        for (int m = 0; m < 4; m++) {
            h4 b = *reinterpret_cast<const h4*>(qp + m * 16 * D_);
#pragma unroll
            for (int j = 0; j < 4; j++) {
                f4 s = __builtin_amdgcn_mfma_f32_16x16x16f16(a[j], b, z4, 0, 0, 0);
#pragma unroll
                for (int i = 0; i < 4; i++) l[j][i] += fast_exp2(s[i]);
            }
        }
        qp += 64 * D_;
    }
#pragma unroll
    for (int off = 1; off < 16; off <<= 1)
#pragma unroll
        for (int j = 0; j < 4; j++)
#pragma unroll
            for (int i = 0; i < 4; i++)
                l[j][i] += __shfl_xor(l[j][i], off, 64);

    if (row == 0) {
        float* lp = Lp + ((size_t)z * NH_ + nh) * T_;
#pragma unroll
        for (int j = 0; j < 4; j++)
            *reinterpret_cast<f4*>(lp + (kt0 + j) * 16 + quad * 4) = l[j];
    }
}

// ---------------------------------------------------------------------------
// K3: attn — rl prologue (fp16, LDS) + k-split x4 PV; V scaled in-register.
//     Per 32-k: two k16 S-MFMAs with PERMUTED K rows -> A-frag of 16x16x32 PV.
//     Manual unroll x4 (imm-offset loads).  grid (NH, 8, 4) x 256.
// ---------------------------------------------------------------------------
__global__ __launch_bounds__(256, 8) void attn_kernel(
    const _Float16* __restrict__ Qh, const _Float16* __restrict__ Kh,
    const _Float16* __restrict__ Vt, const float* __restrict__ Lp,
    float* __restrict__ PO)
{
    __shared__ __align__(16) _Float16 rlh[512];
    int tid = threadIdx.x;
    int lane = tid & 63, wave = tid >> 6;
    int row = lane & 15, quad = lane >> 4;
    int nh = blockIdx.x;
    int qt0 = (blockIdx.y * 4 + wave) * 4;    // first of 4 q-tiles
    int z = blockIdx.z;
    int k_lo = z * (T_ / 4);

    // prologue: rlh[i] = fp16( 1 / sum_zz Lp[zz][nh][k_lo+i] ),  i in [0,512)
    {
        int kk = tid * 2;
        float s0 = 0.f, s1 = 0.f;
#pragma unroll
        for (int zz = 0; zz < 4; zz++) {
            float2 lv = *reinterpret_cast<const float2*>(
                Lp + ((size_t)zz * NH_ + nh) * T_ + k_lo + kk);
            s0 += lv.x; s1 += lv.y;
        }
        g2 pk = __builtin_amdgcn_cvt_pkrtz(1.0f / s0, 1.0f / s1);
        *reinterpret_cast<g2*>(&rlh[kk]) = pk;
    }
    __syncthreads();

    const _Float16* Kb = Kh + (size_t)nh * T_ * D_;
    const _Float16* Qb = Qh + (size_t)nh * T_ * D_;
    const _Float16* Vb = Vt + (size_t)nh * D_ * T_ + (size_t)row * T_;

    h4 b[4];
#pragma unroll
    for (int j = 0; j < 4; j++)
        b[j] = *reinterpret_cast<const h4*>(Qb + ((qt0 + j) * 16 + row) * D_ + quad * 4);

    f4 o[4];
#pragma unroll
    for (int j = 0; j < 4; j++) o[j] = (f4){0.f, 0.f, 0.f, 0.f};
    f4 z4 = {0.f, 0.f, 0.f, 0.f};

    int pr = ((row & 12) << 1) | (row & 3);   // permuted K-row offset

    const _Float16* kp = Kb + (size_t)(k_lo + pr) * D_ + quad * 4;
    const _Float16* vp = Vb + k_lo + quad * 8;
    const _Float16* rp = rlh + quad * 8;
    for (int it = 0; it < (T_ / 4) / 128; it++) {      // 4 outer iters, 4x32k each
#pragma unroll
        for (int m = 0; m < 4; m++) {
            h4 a0 = *reinterpret_cast<const h4*>(kp + m * 32 * D_);
            h4 a1 = *reinterpret_cast<const h4*>(kp + m * 32 * D_ + 4 * D_);
            h8 v = *reinterpret_cast<const h8*>(vp + m * 32);
            h8 rv = *reinterpret_cast<const h8*>(rp + m * 32);
            v = v * rv;                        // fold 1/l into V fragment
#pragma unroll
            for (int j = 0; j < 4; j++) {
                f4 s0 = __builtin_amdgcn_mfma_f32_16x16x16f16(a0, b[j], z4, 0, 0, 0);
                f4 s1 = __builtin_amdgcn_mfma_f32_16x16x16f16(a1, b[j], z4, 0, 0, 0);
                union { h4 h[2]; h8 h8v; } p;
                p.h[0] = pack4_f16(fast_exp2(s0[0]), fast_exp2(s0[1]),
                                   fast_exp2(s0[2]), fast_exp2(s0[3]));
                p.h[1] = pack4_f16(fast_exp2(s1[0]), fast_exp2(s1[1]),
                                   fast_exp2(s1[2]), fast_exp2(s1[3]));
                o[j] = __builtin_amdgcn_mfma_f32_16x16x32_f16(p.h8v, v, o[j], 0, 0, 0);
            }
        }
        kp += 128 * D_;
        vp += 128;
        rp += 128;
    }
    int n = nh >> 2, h = nh & 3;
    float* po = PO + (size_t)z * N_ * T_ * E_ + (size_t)n * T_ * E_ + h * D_ + row;
#pragma unroll
    for (int j = 0; j < 4; j++)
#pragma unroll
        for (int i = 0; i < 4; i++) {
            int q0 = (qt0 + j) * 16 + quad * 4 + i;
            po[(size_t)q0 * E_] = o[j][i];
        }
}

// ---------------------------------------------------------------------------
// K4: fc — out = (sum_z PO[z]) @ Wfc + bfc via 16x16x32 MFMA on Wt.
//     wave: one 16-row M-tile; 2048 tiles -> 512 blocks.
// ---------------------------------------------------------------------------
__global__ __launch_bounds__(256) void fc_kernel(
    const float* __restrict__ PO, const _Float16* __restrict__ Wt,
    const float* __restrict__ bfc, float* __restrict__ out)
{
    int tid = threadIdx.x;
    int lane = tid & 63, wave = tid >> 6;
    int row = lane & 15, quad = lane >> 4;
    int g = blockIdx.x * 4 + wave;             // M-tile id, 2048 total
    int r0 = g * 16;
    size_t base = (size_t)(r0 + row) * E_;
    const size_t zstride = (size_t)N_ * T_ * E_ / 4;   // f4 units

    h8 a[2];
#pragma unroll
    for (int half = 0; half < 2; half++) {
        f4 u0 = {0.f,0.f,0.f,0.f}, u1 = {0.f,0.f,0.f,0.f};
#pragma unroll
        for (int zz = 0; zz < 4; zz++) {
            const f4* p = reinterpret_cast<const f4*>(PO) + zz * zstride + base / 4;
            f4 w0 = p[half * 8 + quad * 2];
            f4 w1 = p[half * 8 + quad * 2 + 1];
#pragma unroll
            for (int i = 0; i < 4; i++) { u0[i] += w0[i]; u1[i] += w1[i]; }
        }
        union { h4 h[2]; h8 v; } pk;
        pk.h[0] = pack4_f16(u0[0], u0[1], u0[2], u0[3]);
        pk.h[1] = pack4_f16(u1[0], u1[1], u1[2], u1[3]);
        a[half] = pk.v;
    }
    f4 acc[4];
#pragma unroll
    for (int ne = 0; ne < 4; ne++) {
        const _Float16* wtb = Wt + (size_t)(ne * 16 + row) * 64;
        h8 b0 = *reinterpret_cast<const h8*>(wtb + quad * 8);
        h8 b1 = *reinterpret_cast<const h8*>(wtb + 32 + quad * 8);
        acc[ne] = __builtin_amdgcn_mfma_f32_16x16x32_f16(a[0], b0, (f4){0.f,0.f,0.f,0.f}, 0, 0, 0);
        acc[ne] = __builtin_amdgcn_mfma_f32_16x16x32_f16(a[1], b1, acc[ne], 0, 0, 0);
    }
#pragma unroll
    for (int ne = 0; ne < 4; ne++) {
        float bias = bfc[ne * 16 + row];
#pragma unroll
        for (int i = 0; i < 4; i++)
            out[(size_t)(r0 + quad * 4 + i) * E_ + ne * 16 + row] = acc[ne][i] + bias;
    }
}

extern "C" void kernel_launch(void* const* d_in, const int* in_sizes, int n_in,
                              void* d_out, int out_size, void* d_ws, size_t ws_size,
                              hipStream_t stream) {
    (void)in_sizes; (void)n_in; (void)out_size; (void)ws_size;
    const float* value = (const float*)d_in[0];
    const float* key   = (const float*)d_in[1];
    const float* query = (const float*)d_in[2];
    const float* Wq    = (const float*)d_in[3];
    const float* bq    = (const float*)d_in[4];
    const float* Wk    = (const float*)d_in[5];
    const float* bk    = (const float*)d_in[6];
    const float* Wv    = (const float*)d_in[7];
    const float* bv    = (const float*)d_in[8];
    const float* Wfc   = (const float*)d_in[9];
    const float* bfc   = (const float*)d_in[10];
    float* out = (float*)d_out;

    // ws bytes: Qh 0-4M | Kh 4-8M | Vt 8-12M | Wt 12M | Lp 13-15M | PO 15-47M
    char* ws = (char*)d_ws;
    _Float16* Qh  = (_Float16*)(ws);
    _Float16* Kh  = (_Float16*)(ws + (4u << 20));
    _Float16* Vt  = (_Float16*)(ws + (8u << 20));
    _Float16* Wt  = (_Float16*)(ws + (12u << 20));
    float*    Lp  = (float*)   (ws + (13u << 20));
    float*    PO  = (float*)   (ws + (15u << 20));

    proj_kernel<<<dim3(512, 4), 256, 0, stream>>>(
        query, Wq, bq, key, Wk, bk, value, Wv, bv, Wfc, Qh, Kh, Vt, Wt);
    stats_kernel<<<dim3(NH_, 8, 4), 256, 0, stream>>>(Qh, Kh, Lp);
    attn_kernel<<<dim3(NH_, 8, 4), 256, 0, stream>>>(Qh, Kh, Vt, Lp, PO);
    fc_kernel<<<512, 256, 0, stream>>>(PO, Wt, bfc, out);
}

// Round 13
// 173.334 us; speedup vs baseline: 3.0720x; 1.3221x over previous
//
#include <hip/hip_runtime.h>

// Problem constants: B=1, N=16, T=2048, E=64, H=4, D=16
#define N_ 16
#define T_ 2048
#define E_ 64
#define H_ 4
#define D_ 16
#define NH_ 64            // N_*H_
#define SEXP_ 0.18033688f // 0.125 * log2(e):  exp(s/8) == exp2(s*SEXP_)

typedef __attribute__((ext_vector_type(4))) _Float16 h4;
typedef __attribute__((ext_vector_type(8))) _Float16 h8;
typedef __attribute__((ext_vector_type(2))) __fp16 g2;
typedef __attribute__((ext_vector_type(4))) float f4;

#if __has_builtin(__builtin_amdgcn_exp2f)
__device__ inline float fast_exp2(float x) { return __builtin_amdgcn_exp2f(x); }
#else
__device__ inline float fast_exp2(float x) {
    float r; asm("v_exp_f32 %0, %1" : "=v"(r) : "v"(x)); return r;
}
#endif

__device__ inline h4 pack4_f16(float a, float b, float c, float d) {
    union { g2 g[2]; h4 h; } u;
    u.g[0] = __builtin_amdgcn_cvt_pkrtz(a, b);
    u.g[1] = __builtin_amdgcn_cvt_pkrtz(c, d);
    return u.h;
}

// ---------------------------------------------------------------------------
// K1: fused projections (y=0 Q pre-scaled, y=1 K, y=2 V-transposed, y=3 Wfc^T)
// ---------------------------------------------------------------------------
__global__ __launch_bounds__(256) void proj_kernel(
    const float* __restrict__ xq, const float* __restrict__ Wq, const float* __restrict__ bq,
    const float* __restrict__ xk, const float* __restrict__ Wk, const float* __restrict__ bk,
    const float* __restrict__ xv, const float* __restrict__ Wv, const float* __restrict__ bv,
    const float* __restrict__ Wfc,
    _Float16* __restrict__ Qh, _Float16* __restrict__ Kh, _Float16* __restrict__ Vt,
    _Float16* __restrict__ Wt)
{
    int tid = threadIdx.x;
    int y = blockIdx.y;
    if (y == 3) {
        if (blockIdx.x < 16) {
            int k = blockIdx.x * 4 + (tid >> 6);
            int e = tid & 63;
            Wt[e * 64 + k] = (_Float16)Wfc[k * 64 + e];
        }
        return;
    }
    const float* x = (y == 0) ? xq : (y == 1) ? xk : xv;
    const float* W = (y == 0) ? Wq : (y == 1) ? Wk : Wv;
    const float* b = (y == 0) ? bq : (y == 1) ? bk : bv;
    const float sc = (y == 0) ? SEXP_ : 1.0f;

    __shared__ float Wl[D_ * D_];
    __shared__ float bl[D_];
    Wl[tid] = W[tid];
    if (tid < D_) bl[tid] = b[tid];
    __syncthreads();

    int r = blockIdx.x * 256 + tid;
    int h, t, n;
    if (y == 2) {          // t fastest: coalesced transposed stores
        t = r & (T_ - 1);
        h = (r >> 11) & (H_ - 1);
        n = r >> 13;
    } else {               // h fastest: coalesced reads
        h = r & (H_ - 1);
        t = (r >> 2) & (T_ - 1);
        n = r >> 13;
    }

    const float4* xp4 = reinterpret_cast<const float4*>(
        x + ((size_t)(n * T_ + t) * E_ + h * D_));
    float xv_[D_];
#pragma unroll
    for (int i = 0; i < 4; i++) {
        float4 v = xp4[i];
        xv_[4*i] = v.x; xv_[4*i+1] = v.y; xv_[4*i+2] = v.z; xv_[4*i+3] = v.w;
    }
    float acc[D_];
#pragma unroll
    for (int i = 0; i < D_; i++) acc[i] = bl[i];
#pragma unroll
    for (int j = 0; j < D_; j++) {
        float xj = xv_[j];
#pragma unroll
        for (int i = 0; i < D_; i++) acc[i] = fmaf(xj, Wl[j * D_ + i], acc[i]);
    }
    if (y == 2) {
        _Float16* vb = Vt + (size_t)(n * H_ + h) * D_ * T_ + t;
#pragma unroll
        for (int d = 0; d < D_; d++) vb[(size_t)d * T_] = (_Float16)acc[d];
    } else {
        _Float16 ob[16];
#pragma unroll
        for (int i = 0; i < D_; i++) ob[i] = (_Float16)(acc[i] * sc);
        _Float16* o = (y == 0) ? Qh : Kh;
        uint4* dst = reinterpret_cast<uint4*>(o + (size_t)((n * H_ + h) * T_ + t) * D_);
        dst[0] = reinterpret_cast<uint4*>(ob)[0];
        dst[1] = reinterpret_cast<uint4*>(ob)[1];
    }
}

// ---------------------------------------------------------------------------
// K2: stats — partial column sums Lp[z][nh][k] = sum_{q in z-chunk} exp2(S')
//     4 k-tiles/wave, q-split x4.  grid (NH, 8, 4) x 256.  (R9-exact form;
//     NO min-waves launch_bounds — R12's (256,8) forced 32 VGPR -> 250 MB
//     of scratch spill traffic, 5x slowdown.)
// ---------------------------------------------------------------------------
__global__ __launch_bounds__(256) void stats_kernel(
    const _Float16* __restrict__ Qh, const _Float16* __restrict__ Kh,
    float* __restrict__ Lp)
{
    int tid = threadIdx.x;
    int lane = tid & 63, wave = tid >> 6;
    int row = lane & 15, quad = lane >> 4;
    int nh = blockIdx.x;
    int kt0 = (blockIdx.y * 4 + wave) * 4;    // first of 4 k-tiles
    int z = blockIdx.z;
    const _Float16* Kb = Kh + (size_t)nh * T_ * D_;
    const _Float16* Qb = Qh + (size_t)nh * T_ * D_;

    h4 a[4];
#pragma unroll
    for (int j = 0; j < 4; j++)
        a[j] = *reinterpret_cast<const h4*>(Kb + ((kt0 + j) * 16 + row) * D_ + quad * 4);

    f4 l[4];
#pragma unroll
    for (int j = 0; j < 4; j++) l[j] = (f4){0.f, 0.f, 0.f, 0.f};
    f4 z4 = {0.f, 0.f, 0.f, 0.f};

    int q_lo = z * (T_ / 4), q_hi = q_lo + T_ / 4;
#pragma unroll 4
    for (int q0 = q_lo; q0 < q_hi; q0 += 16) {
        h4 b = *reinterpret_cast<const h4*>(Qb + (q0 + row) * D_ + quad * 4);
#pragma unroll
        for (int j = 0; j < 4; j++) {
            f4 s = __builtin_amdgcn_mfma_f32_16x16x16f16(a[j], b, z4, 0, 0, 0);
#pragma unroll
            for (int i = 0; i < 4; i++) l[j][i] += fast_exp2(s[i]);
        }
    }
#pragma unroll
    for (int off = 1; off < 16; off <<= 1)
#pragma unroll
        for (int j = 0; j < 4; j++)
#pragma unroll
            for (int i = 0; i < 4; i++)
                l[j][i] += __shfl_xor(l[j][i], off, 64);

    if (row == 0) {
        float* lp = Lp + ((size_t)z * NH_ + nh) * T_;
#pragma unroll
        for (int j = 0; j < 4; j++)
            *reinterpret_cast<f4*>(lp + (kt0 + j) * 16 + quad * 4) = l[j];
    }
}

// ---------------------------------------------------------------------------
// K3: attn — rl prologue (fp16, LDS; combine fused) + k-split x4 PV.
//     Per 32-k: two k16 S-MFMAs with PERMUTED K rows -> A-frag of 16x16x32 PV.
//     V scaled in-register by rlh.  grid (NH, 8, 4) x 256.  (R9 loop form.)
// ---------------------------------------------------------------------------
__global__ __launch_bounds__(256) void attn_kernel(
    const _Float16* __restrict__ Qh, const _Float16* __restrict__ Kh,
    const _Float16* __restrict__ Vt, const float* __restrict__ Lp,
    float* __restrict__ PO)
{
    __shared__ __align__(16) _Float16 rlh[512];
    int tid = threadIdx.x;
    int lane = tid & 63, wave = tid >> 6;
    int row = lane & 15, quad = lane >> 4;
    int nh = blockIdx.x;
    int qt0 = (blockIdx.y * 4 + wave) * 4;    // first of 4 q-tiles
    int z = blockIdx.z;
    int k_lo = z * (T_ / 4);

    // prologue: rlh[i] = fp16( 1 / sum_zz Lp[zz][nh][k_lo+i] ),  i in [0,512)
    {
        int kk = tid * 2;
        float s0 = 0.f, s1 = 0.f;
#pragma unroll
        for (int zz = 0; zz < 4; zz++) {
            float2 lv = *reinterpret_cast<const float2*>(
                Lp + ((size_t)zz * NH_ + nh) * T_ + k_lo + kk);
            s0 += lv.x; s1 += lv.y;
        }
        g2 pk = __builtin_amdgcn_cvt_pkrtz(1.0f / s0, 1.0f / s1);
        *reinterpret_cast<g2*>(&rlh[kk]) = pk;
    }
    __syncthreads();

    const _Float16* Kb = Kh + (size_t)nh * T_ * D_;
    const _Float16* Qb = Qh + (size_t)nh * T_ * D_;
    const _Float16* Vb = Vt + (size_t)nh * D_ * T_ + (size_t)row * T_;

    h4 b[4];
#pragma unroll
    for (int j = 0; j < 4; j++)
        b[j] = *reinterpret_cast<const h4*>(Qb + ((qt0 + j) * 16 + row) * D_ + quad * 4);

    f4 o[4];
#pragma unroll
    for (int j = 0; j < 4; j++) o[j] = (f4){0.f, 0.f, 0.f, 0.f};
    f4 z4 = {0.f, 0.f, 0.f, 0.f};

    int pr = ((row & 12) << 1) | (row & 3);   // permuted K-row offset

    int k_hi = k_lo + T_ / 4;
#pragma unroll 2
    for (int k0 = k_lo; k0 < k_hi; k0 += 32) {
        h4 a0 = *reinterpret_cast<const h4*>(Kb + (k0 + pr) * D_ + quad * 4);
        h4 a1 = *reinterpret_cast<const h4*>(Kb + (k0 + pr + 4) * D_ + quad * 4);
        h8 v = *reinterpret_cast<const h8*>(Vb + k0 + quad * 8);
        h8 rv = *reinterpret_cast<const h8*>(&rlh[(k0 - k_lo) + quad * 8]);
        v = v * rv;                            // fold 1/l into V fragment
#pragma unroll
        for (int j = 0; j < 4; j++) {
            f4 s0 = __builtin_amdgcn_mfma_f32_16x16x16f16(a0, b[j], z4, 0, 0, 0);
            f4 s1 = __builtin_amdgcn_mfma_f32_16x16x16f16(a1, b[j], z4, 0, 0, 0);
            union { h4 h[2]; h8 h8v; } p;
            p.h[0] = pack4_f16(fast_exp2(s0[0]), fast_exp2(s0[1]),
                               fast_exp2(s0[2]), fast_exp2(s0[3]));
            p.h[1] = pack4_f16(fast_exp2(s1[0]), fast_exp2(s1[1]),
                               fast_exp2(s1[2]), fast_exp2(s1[3]));
            o[j] = __builtin_amdgcn_mfma_f32_16x16x32_f16(p.h8v, v, o[j], 0, 0, 0);
        }
    }
    int n = nh >> 2, h = nh & 3;
    float* po = PO + (size_t)z * N_ * T_ * E_ + (size_t)n * T_ * E_ + h * D_ + row;
#pragma unroll
    for (int j = 0; j < 4; j++)
#pragma unroll
        for (int i = 0; i < 4; i++) {
            int q0 = (qt0 + j) * 16 + quad * 4 + i;
            po[(size_t)q0 * E_] = o[j][i];
        }
}

// ---------------------------------------------------------------------------
// K4: fc — out = (sum_z PO[z]) @ Wfc + bfc via 16x16x32 MFMA on Wt.
//     wave: one 16-row M-tile; 2048 tiles -> 512 blocks.
// ---------------------------------------------------------------------------
__global__ __launch_bounds__(256) void fc_kernel(
    const float* __restrict__ PO, const _Float16* __restrict__ Wt,
    const float* __restrict__ bfc, float* __restrict__ out)
{
    int tid = threadIdx.x;
    int lane = tid & 63, wave = tid >> 6;
    int row = lane & 15, quad = lane >> 4;
    int g = blockIdx.x * 4 + wave;             // M-tile id, 2048 total
    int r0 = g * 16;
    size_t base = (size_t)(r0 + row) * E_;
    const size_t zstride = (size_t)N_ * T_ * E_ / 4;   // f4 units

    h8 a[2];
#pragma unroll
    for (int half = 0; half < 2; half++) {
        f4 u0 = {0.f,0.f,0.f,0.f}, u1 = {0.f,0.f,0.f,0.f};
#pragma unroll
        for (int zz = 0; zz < 4; zz++) {
            const f4* p = reinterpret_cast<const f4*>(PO) + zz * zstride + base / 4;
            f4 w0 = p[half * 8 + quad * 2];
            f4 w1 = p[half * 8 + quad * 2 + 1];
#pragma unroll
            for (int i = 0; i < 4; i++) { u0[i] += w0[i]; u1[i] += w1[i]; }
        }
        union { h4 h[2]; h8 v; } pk;
        pk.h[0] = pack4_f16(u0[0], u0[1], u0[2], u0[3]);
        pk.h[1] = pack4_f16(u1[0], u1[1], u1[2], u1[3]);
        a[half] = pk.v;
    }
    f4 acc[4];
#pragma unroll
    for (int ne = 0; ne < 4; ne++) {
        const _Float16* wtb = Wt + (size_t)(ne * 16 + row) * 64;
        h8 b0 = *reinterpret_cast<const h8*>(wtb + quad * 8);
        h8 b1 = *reinterpret_cast<const h8*>(wtb + 32 + quad * 8);
        acc[ne] = __builtin_amdgcn_mfma_f32_16x16x32_f16(a[0], b0, (f4){0.f,0.f,0.f,0.f}, 0, 0, 0);
        acc[ne] = __builtin_amdgcn_mfma_f32_16x16x32_f16(a[1], b1, acc[ne], 0, 0, 0);
    }
#pragma unroll
    for (int ne = 0; ne < 4; ne++) {
        float bias = bfc[ne * 16 + row];
#pragma unroll
        for (int i = 0; i < 4; i++)
            out[(size_t)(r0 + quad * 4 + i) * E_ + ne * 16 + row] = acc[ne][i] + bias;
    }
}

extern "C" void kernel_launch(void* const* d_in, const int* in_sizes, int n_in,
                              void* d_out, int out_size, void* d_ws, size_t ws_size,
                              hipStream_t stream) {
    (void)in_sizes; (void)n_in; (void)out_size; (void)ws_size;
    const float* value = (const float*)d_in[0];
    const float* key   = (const float*)d_in[1];
    const float* query = (const float*)d_in[2];
    const float* Wq    = (const float*)d_in[3];
    const float* bq    = (const float*)d_in[4];
    const float* Wk    = (const float*)d_in[5];
    const float* bk    = (const float*)d_in[6];
    const float* Wv    = (const float*)d_in[7];
    const float* bv    = (const float*)d_in[8];
    const float* Wfc   = (const float*)d_in[9];
    const float* bfc   = (const float*)d_in[10];
    float* out = (float*)d_out;

    // ws bytes: Qh 0-4M | Kh 4-8M | Vt 8-12M | Wt 12M | Lp 13-15M | PO 15-47M
    char* ws = (char*)d_ws;
    _Float16* Qh  = (_Float16*)(ws);
    _Float16* Kh  = (_Float16*)(ws + (4u << 20));
    _Float16* Vt  = (_Float16*)(ws + (8u << 20));
    _Float16* Wt  = (_Float16*)(ws + (12u << 20));
    float*    Lp  = (float*)   (ws + (13u << 20));
    float*    PO  = (float*)   (ws + (15u << 20));

    proj_kernel<<<dim3(512, 4), 256, 0, stream>>>(
        query, Wq, bq, key, Wk, bk, value, Wv, bv, Wfc, Qh, Kh, Vt, Wt);
    stats_kernel<<<dim3(NH_, 8, 4), 256, 0, stream>>>(Qh, Kh, Lp);
    attn_kernel<<<dim3(NH_, 8, 4), 256, 0, stream>>>(Qh, Kh, Vt, Lp, PO);
    fc_kernel<<<512, 256, 0, stream>>>(PO, Wt, bfc, out);
}